// Round 1
// baseline (369.479 us; speedup 1.0000x reference)
//
#include <hip/hip_runtime.h>
#include <hip/hip_bf16.h>

#define BLOCK   512     // 8 waves; wave w owns channels w*16..w*16+15, all 4 gates
#define NSAMP   16
#define HDIM    128
#define DDIM    16
#define NOBJ    6
#define NSLOT   14

typedef __attribute__((ext_vector_type(8))) short bf16x8;
typedef __attribute__((ext_vector_type(4))) float f32x4;

constexpr int pc6(int m)  { int c = 0; for (int i = 0; i < 6; ++i) c += (m >> i) & 1; return c; }
constexpr int msb6(int m) { int b = -1; for (int i = 0; i < 6; ++i) if (m & (1 << i)) b = i; return b; }

// Compile-time BFS plan, 14-slot allocator with multi-phase recycling (verified R11/R13).
struct PNode { int jo, ps, sl; bool bar; };
struct Plan2 { PNode nd[63]; int lvlStart[8]; };
constexpr Plan2 make_plan2() {
    Plan2 P{};
    int slotOf[64] = {};
    bool busy[NSLOT] = {};
    int k = 0;
    for (int d = 1; d <= 6; ++d) {
        P.lvlStart[d] = k;
        for (int M = 1; M < 64; ++M) {               // leaves (msb==5): no slot
            if (pc6(M) != d || msb6(M) != 5) continue;
            P.nd[k].jo = 5;
            P.nd[k].ps = (d == 1) ? -1 : slotOf[M & ~(1 << 5)];
            P.nd[k].sl = -1;
            P.nd[k].bar = false;
            ++k;
        }
        int pend[20] = {}; int np = 0;
        for (int M = 1; M < 64; ++M)
            if (pc6(M) == d && msb6(M) < 5) pend[np++] = M;
        int key[20] = {};
        for (int i = 0; i < np; ++i) {
            if (d == 1) { key[i] = 0; continue; }
            const int par = pend[i] & ~(1 << msb6(pend[i]));
            int c2 = 0;
            for (int j2 = 0; j2 < np; ++j2)
                if ((pend[j2] & ~(1 << msb6(pend[j2]))) == par) ++c2;
            key[i] = c2;
        }
        for (int a = 0; a < np; ++a)
            for (int b2 = a + 1; b2 < np; ++b2)
                if (key[b2] < key[a]) {
                    int tm = key[a]; key[a] = key[b2]; key[b2] = tm;
                    tm = pend[a]; pend[a] = pend[b2]; pend[b2] = tm;
                }
        bool placed[20] = {};
        int nplaced = 0;
        bool firstPhase = true;
        while (nplaced < np) {
            bool needBar = !firstPhase;
            bool any = false;
            for (int i = 0; i < np; ++i) {
                if (placed[i]) continue;
                int fs = -1;
                for (int s = 0; s < NSLOT; ++s) if (!busy[s]) { fs = s; break; }
                if (fs < 0) break;
                const int M = pend[i]; const int hi = msb6(M);
                busy[fs] = true; slotOf[M] = fs;
                P.nd[k].jo = hi;
                P.nd[k].ps = (d == 1) ? -1 : slotOf[M & ~(1 << hi)];
                P.nd[k].sl = fs;
                P.nd[k].bar = needBar; needBar = false;
                ++k; placed[i] = true; ++nplaced; any = true;
            }
            firstPhase = false;
            if (nplaced < np) {
                if (!any) break;
                for (int M = 1; M < 64; ++M) {
                    if (pc6(M) != d - 1 || msb6(M) >= 5) continue;
                    bool allp = true;
                    for (int i = 0; i < np; ++i)
                        if (!placed[i] &&
                            ((pend[i] & ~(1 << msb6(pend[i]))) == M)) allp = false;
                    if (allp) busy[slotOf[M]] = false;
                }
            }
        }
        for (int s = 0; s < NSLOT; ++s) busy[s] = false;
        for (int M = 1; M < 64; ++M)
            if (pc6(M) == d && msb6(M) < 5) busy[slotOf[M]] = true;
    }
    P.lvlStart[7] = k;
    return P;
}
constexpr Plan2 PL2 = make_plan2();
static_assert(PL2.lvlStart[7] == 63, "plan must cover all 63 nodes");

#define LOG2E   1.44269504f
#define TWOL2E  2.88539008f
#define SLOT_SH 2048            // shorts per slot (4 KB), h pool

__device__ __forceinline__ unsigned short f2bf(float x) {
    union { float f; unsigned int u; } a; a.f = x;
    unsigned int r = (a.u + 0x7FFFu + ((a.u >> 16) & 1u)) >> 16;
    return (unsigned short)r;
}
__device__ __forceinline__ unsigned pk2(float a, float b) {
    union { __hip_bfloat162 h; unsigned u; } z;
    z.h = __float22bfloat162_rn(float2{a, b});
    return z.u;
}
__device__ __forceinline__ float bflo(unsigned p) {
    union { unsigned u; float f; } a; a.u = p << 16; return a.f;
}
__device__ __forceinline__ float bfhi(unsigned p) {
    union { unsigned u; float f; } a; a.u = p & 0xFFFF0000u; return a.f;
}

// h pool: hs[((slot*16 + kslot)*NSAMP + n)*8 + j] = h[ch = kslot*8+j][sample n]
//   B-frag chunk q, lane (quad,m16): kslot = q*4+quad -> 16B-aligned ds_read_b128
//   wave w writes ch = w*16+quad*4+r at kslot = w*2+(quad>>1), j = (quad&1)*4+r
// c state: LANE-PRIVATE (producer lane == consumer lane for every (ch,sample)),
//   held in registers c_reg[NSLOT] (uint2 = 4x bf16), statically indexed after
//   full unroll (ps/sl are constexpr). This removes the 56 KB csb pool so two
//   blocks fit per CU (LDS 63.5 KB), doubling waves/SIMD from 2 to 4.

__global__ __launch_bounds__(BLOCK)
__attribute__((amdgpu_waves_per_eu(4)))   // demand 4 waves/EU: VGPR cap 128 (2 blocks/CU)
void subset_lstm_skew_kernel(
    const float* __restrict__ x_input,
    const float* __restrict__ W_ih,
    const float* __restrict__ W_hh,
    const float* __restrict__ b_ih,
    const float* __restrict__ b_hh,
    const float* __restrict__ fc1_W,
    const float* __restrict__ fc1_b,
    const float* __restrict__ fc2_W,
    const float* __restrict__ fc2_b,
    float* __restrict__ out)
{
    __shared__ __align__(16) unsigned short hs [NSLOT * SLOT_SH];       // 56 KB
    __shared__ __align__(16) unsigned short xb[NOBJ * 4 * NSAMP * 8];   // 6 KB
    float* s_maxh  = (float*)hs;                 // 8 KB  (post-LSTM alias)
    float* s_fc1   = (float*)(hs + 4096);        // 16 KB (post-LSTM alias)
    float* s_logit = (float*)xb;

    const int t      = threadIdx.x;
    const int w      = t >> 6;
    const int lane   = t & 63;
    const int quad   = lane >> 4;
    const int m16    = lane & 15;
    const int s_base = blockIdx.x * NSAMP;

    // ---- x B-chunks: xb[obj][quad'][n][j]; quad2 j0 = 1.0 (bias lane), quad3 zero ----
    for (int idx = t; idx < NOBJ * 4 * NSAMP * 8; idx += BLOCK) {
        const int j = idx & 7, n = (idx >> 3) & 15, q = (idx >> 7) & 3, obj = idx >> 9;
        float v;
        if (q < 2) v = x_input[(s_base + n) * (NOBJ * DDIM) + obj * DDIM + q * 8 + j];
        else       v = (q == 2 && j == 0) ? 1.0f : 0.0f;
        xb[idx] = f2bf(v);
    }

    // ---- persistent A-frags wf[gate][chunk], PRE-SCALED (verified R8-R13) ----
    bf16x8 wf[4][5];
    #pragma unroll
    for (int g = 0; g < 4; ++g) {
        const float sc = (g == 2) ? TWOL2E : -LOG2E;
        const int grow = g * HDIM + w * 16 + m16;
        const float* whr = W_hh + grow * HDIM;
        const float* wir = W_ih + grow * DDIM;
        #pragma unroll
        for (int q = 0; q < 4; ++q) {
            union { unsigned short u[8]; bf16x8 v; } pk;
            #pragma unroll
            for (int j = 0; j < 8; ++j)
                pk.u[j] = f2bf(sc * whr[q * 32 + quad * 8 + j]);
            wf[g][q] = pk.v;
        }
        {
            union { unsigned short u[8]; bf16x8 v; } pk;
            #pragma unroll
            for (int j = 0; j < 8; ++j) {
                float v = 0.0f;
                if (quad < 2) v = sc * wir[quad * 8 + j];
                else if (quad == 2 && j == 0) v = sc * (b_ih[grow] + b_hh[grow]);
                pk.u[j] = f2bf(v);
            }
            wf[g][4] = pk.v;
        }
    }

    float mh[4] = {-1e30f, -1e30f, -1e30f, -1e30f};
    const int kslot = w * 2 + (quad >> 1);
    uint2 c_reg[NSLOT];   // lane-private c state, 4x bf16 per slot, static idx

    // GEMM for node (jo, ps)
    auto mfma_node = [&](f32x4 (&acc)[4], int jo, int ps) {
        {
            const bf16x8 bfx = *(const bf16x8*)&xb[((jo * 4 + quad) * NSAMP + m16) * 8];
            #pragma unroll
            for (int g = 0; g < 4; ++g)
                acc[g] = __builtin_amdgcn_mfma_f32_16x16x32_bf16(
                    wf[g][4], bfx, f32x4{0.f, 0.f, 0.f, 0.f}, 0, 0, 0);
        }
        if (ps >= 0) {
            #pragma unroll
            for (int q = 0; q < 4; ++q) {
                const bf16x8 bh = *(const bf16x8*)
                    &hs[((ps * 16 + q * 4 + quad) * NSAMP + m16) * 8];
                #pragma unroll
                for (int g = 0; g < 4; ++g)
                    acc[g] = __builtin_amdgcn_mfma_f32_16x16x32_bf16(
                        wf[g][q], bh, acc[g], 0, 0, 0);
            }
        }
    };

    // fused pointwise (verified R9-R13); c from/to registers
    auto pointwise_node = [&](const f32x4 (&acc)[4], int ps, int sl) {
        uint2 cpk;
        if (ps >= 0) cpk = c_reg[ps];
        else         { cpk.x = 0u; cpk.y = 0u; }
        float cn4[4], hn4[4];
        #pragma unroll
        for (int r = 0; r < 4; ++r) {
            const unsigned p = (r < 2) ? cpk.x : cpk.y;
            const float cprev = (r & 1) ? bfhi(p) : bflo(p);
            const float u  = 1.0f + __builtin_amdgcn_exp2f(acc[0][r]);
            const float q  = 1.0f + __builtin_amdgcn_exp2f(acc[1][r]);
            const float v  = 1.0f + __builtin_amdgcn_exp2f(acc[2][r]);
            const float qo = 1.0f + __builtin_amdgcn_exp2f(acc[3][r]);
            const float uv  = u * v;
            const float num = fmaf(q, v - 2.0f, cprev * uv);
            const float cn  = num * __builtin_amdgcn_rcpf(q * uv);
            const float wt  = 1.0f + __builtin_amdgcn_exp2f(TWOL2E * cn);
            const float h   = (wt - 2.0f) * __builtin_amdgcn_rcpf(qo * wt);
            cn4[r] = cn; hn4[r] = h;
            mh[r] = fmaxf(mh[r], h);
        }
        if (sl >= 0) {
            c_reg[sl].x = pk2(cn4[0], cn4[1]);
            c_reg[sl].y = pk2(cn4[2], cn4[3]);
            uint2 hw; hw.x = pk2(hn4[0], hn4[1]); hw.y = pk2(hn4[2], hn4[3]);
            *(uint2*)&hs[((sl * 16 + kslot) * NSAMP + m16) * 8 + (quad & 1) * 4] = hw;
        }
    };

    #pragma unroll
    for (int d = 1; d <= 6; ++d) {
        __syncthreads();
        const int kBeg = PL2.lvlStart[d];
        const int kEnd = PL2.lvlStart[d + 1];
        #pragma unroll
        for (int k = kBeg; k < kEnd; ++k) {
            if (PL2.nd[k].bar) __syncthreads();   // recycle barrier (constexpr)
            f32x4 acc[4];
            mfma_node(acc, PL2.nd[k].jo, PL2.nd[k].ps);
            pointwise_node(acc, PL2.nd[k].ps, PL2.nd[k].sl);
        }
    }

    __syncthreads();   // pools dead; reuse hs for epilogue
    {
        float4 v; v.x = mh[0]; v.y = mh[1]; v.z = mh[2]; v.w = mh[3];
        *(float4*)&s_maxh[m16 * HDIM + w * 16 + quad * 4] = v;
    }
    __syncthreads();

    // ---- FC1: f = t&255, sample half t>>8 (8 samples each) ----
    {
        const int f  = t & 255;
        const int sh = t >> 8;
        float a1[8];
        #pragma unroll
        for (int s = 0; s < 8; ++s) a1[s] = fc1_b[f];
        for (int k4 = 0; k4 < HDIM / 4; ++k4) {
            const float4 wv = *(const float4*)&fc1_W[f * HDIM + k4 * 4];
            #pragma unroll
            for (int s = 0; s < 8; ++s) {
                const float4 h4 = *(const float4*)&s_maxh[(sh * 8 + s) * HDIM + k4 * 4];
                a1[s] += wv.x * h4.x + wv.y * h4.y + wv.z * h4.z + wv.w * h4.w;
            }
        }
        #pragma unroll
        for (int s = 0; s < 8; ++s)
            s_fc1[(sh * 8 + s) * 256 + f] = fmaxf(a1[s], 0.0f);
    }
    __syncthreads();

    if (t < NSAMP * 10) {
        const int s = t / 10, a = t % 10;
        float acc2 = fc2_b[a];
        for (int f4 = 0; f4 < 256 / 4; ++f4) {
            const float4 wv = *(const float4*)&fc2_W[a * 256 + f4 * 4];
            const float4 v  = *(const float4*)&s_fc1[s * 256 + f4 * 4];
            acc2 += wv.x * v.x + wv.y * v.y + wv.z * v.z + wv.w * v.w;
        }
        s_logit[s * 10 + a] = acc2;
    }
    __syncthreads();

    if (t < NSAMP) {
        float m = -1e30f;
        #pragma unroll
        for (int a = 0; a < 10; ++a) m = fmaxf(m, s_logit[t * 10 + a]);
        float sum = 0.0f;
        #pragma unroll
        for (int a = 0; a < 10; ++a) sum += __expf(s_logit[t * 10 + a] - m);
        const float lse = m + __logf(sum);
        #pragma unroll
        for (int a = 0; a < 10; ++a)
            out[(s_base + t) * 10 + a] = s_logit[t * 10 + a] - lse;
    }
}

extern "C" void kernel_launch(void* const* d_in, const int* in_sizes, int n_in,
                              void* d_out, int out_size, void* d_ws, size_t ws_size,
                              hipStream_t stream)
{
    (void)d_ws; (void)ws_size; (void)n_in; (void)out_size;

    const float* x   = (const float*)d_in[0];
    const float* Wih = (const float*)d_in[1];
    const float* Whh = (const float*)d_in[2];
    const float* bih = (const float*)d_in[3];
    const float* bhh = (const float*)d_in[4];
    const float* f1w = (const float*)d_in[5];
    const float* f1b = (const float*)d_in[6];
    const float* f2w = (const float*)d_in[7];
    const float* f2b = (const float*)d_in[8];

    const int mb = in_sizes[0] / (NOBJ * DDIM);   // 8192
    dim3 grid(mb / NSAMP), block(BLOCK);
    subset_lstm_skew_kernel<<<grid, block, 0, stream>>>(
        x, Wih, Whh, bih, bhh, f1w, f1b, f2w, f2b, (float*)d_out);
}